// Round 7
// baseline (132.665 us; speedup 1.0000x reference)
//
#include <hip/hip_runtime.h>

#define DD 256
#define BB 64
#define SS 256                       // H*W
#define K2 2.8853900817779268f      // 2*log2(e)
#define LOG2E 1.4426950408889634f

#if __has_builtin(__builtin_amdgcn_exp2f)
#define EXP2(x) __builtin_amdgcn_exp2f(x)
#else
#define EXP2(x) exp2f(x)
#endif

static __device__ __forceinline__ float fast_rcp(float x) {
  return __builtin_amdgcn_rcpf(x);
}

// ---- kernel 1: transpose wv_w into wvT (blocks 0..15) + att_rK = K2*(pe@wo^T+b) (blocks 16..) ----
__global__ __launch_bounds__(256) void k_prep(
    const float* __restrict__ wv_w,
    const float* __restrict__ wo_w, const float* __restrict__ wo_b,
    float* __restrict__ wvT, float* __restrict__ att_r, int T)
{
  const int tid = threadIdx.x;
  if (blockIdx.x < 16) {
    const int bi = blockIdx.x >> 2;   // d-tile
    const int bj = blockIdx.x & 3;    // c-tile
    __shared__ float tile[64 * 65];
#pragma unroll
    for (int p = 0; p < 4; ++p) {
      int row = p * 16 + (tid >> 4);          // local d
      int col = (tid & 15) * 4;               // local c
      float4 v = *reinterpret_cast<const float4*>(wv_w + (size_t)(bi*64 + row)*DD + bj*64 + col);
      tile[row*65 + col + 0] = v.x;
      tile[row*65 + col + 1] = v.y;
      tile[row*65 + col + 2] = v.z;
      tile[row*65 + col + 3] = v.w;
    }
    __syncthreads();
#pragma unroll
    for (int p = 0; p < 4; ++p) {
      int orow = p * 16 + (tid >> 4);   // local c
      int ocol = (tid & 15) * 4;        // local d
      float4 o;
      o.x = tile[(ocol+0)*65 + orow];
      o.y = tile[(ocol+1)*65 + orow];
      o.z = tile[(ocol+2)*65 + orow];
      o.w = tile[(ocol+3)*65 + orow];
      *reinterpret_cast<float4*>(wvT + (size_t)(bj*64 + orow)*DD + bi*64 + ocol) = o;
    }
    return;
  }
  // ---- att_r branch (pre-scaled by K2) ----
  const int t = blockIdx.x - 16;
  if (t >= T) return;
  __shared__ float pe[DD];
  {
    int i = tid >> 1;
    double r = pow(10000.0, -(double)(2*i) / 256.0);
    double ang = (double)t * r;
    pe[tid] = (float)((tid & 1) ? cos(ang) : sin(ang));
  }
  __syncthreads();
  const float4* wr = reinterpret_cast<const float4*>(wo_w + (size_t)tid * DD);
  const float4* pp = reinterpret_cast<const float4*>(pe);
  float acc = 0.f;
#pragma unroll 8
  for (int k = 0; k < 64; ++k) {
    float4 w4 = wr[k]; float4 p4 = pp[k];
    acc = fmaf(w4.x, p4.x, acc);
    acc = fmaf(w4.y, p4.y, acc);
    acc = fmaf(w4.z, p4.z, acc);
    acc = fmaf(w4.w, p4.w, acc);
  }
  att_r[(size_t)t*DD + tid] = K2 * (acc + wo_b[tid]);
}

// ---- kernel 2 (FUSED): att_x GEMM + raw scores ----
// grid (16 sT, 64 b) = 1024 blocks (4/CU, 16 waves/CU), block 256.
// Tile 16s x 256d; thread sg=tid>>5 (2 s), dg=tid&31 (8 d: dg*4..+3, 128+dg*4..+3).
// After GEMM, acc IS att_x (reg-resident) -> score for all T in-register.
__global__ __launch_bounds__(256) void k_attx_score(
    const float* __restrict__ x, const float* __restrict__ wvT,
    const float* __restrict__ wv_b, const float* __restrict__ att_rK,
    const float* __restrict__ we_w,
    float* __restrict__ att_x, float* __restrict__ score, int T)
{
  const int b  = blockIdx.y;
  const int s0 = blockIdx.x * 16;
  const int tid = threadIdx.x;
  const int sg = tid >> 5;             // 0..7
  const int dg = tid & 31;             // 0..31
  const float* xb = x + (size_t)b * DD * SS;   // [c][s]

  __shared__ float wt[2][16 * 256];    // 2 x 16 KB
  __shared__ float xs[2][16 * 16];     // 2 x 1 KB
  __shared__ float scS[32 * 16];       // raw scores [t][sl], 2 KB

  float acc[2][8];
#pragma unroll
  for (int j = 0; j < 2; ++j)
#pragma unroll
    for (int r = 0; r < 8; ++r) acc[j][r] = 0.f;

  // staging sources (flat copies, coalesced)
  const float* wsrc = wvT + (size_t)tid * 4;                               // + cc*16*DD + k*1024
  const float* xsrc = xb + (size_t)(tid >> 2) * SS + s0 + (tid & 3) * 4;   // tid<64: rows 0..15

  float4 wA[4];
  float4 xA = make_float4(0.f, 0.f, 0.f, 0.f);
#pragma unroll
  for (int k = 0; k < 4; ++k)
    wA[k] = *reinterpret_cast<const float4*>(wsrc + k * 1024);
  if (tid < 64) xA = *reinterpret_cast<const float4*>(xsrc);

  int cur = 0;
  for (int cc = 0; cc < 16; ++cc) {
#pragma unroll
    for (int k = 0; k < 4; ++k)
      *reinterpret_cast<float4*>(&wt[cur][tid * 4 + k * 1024]) = wA[k];
    if (tid < 64) *reinterpret_cast<float4*>(&xs[cur][tid * 4]) = xA;
    if (cc < 15) {
#pragma unroll
      for (int k = 0; k < 4; ++k)
        wA[k] = *reinterpret_cast<const float4*>(wsrc + (size_t)(cc + 1) * 16 * DD + k * 1024);
      if (tid < 64) xA = *reinterpret_cast<const float4*>(xsrc + (size_t)(cc + 1) * 16 * SS);
    }
    __syncthreads();                                // buf[cur] ready
#pragma unroll
    for (int ci = 0; ci < 16; ++ci) {
      float2 xv = *reinterpret_cast<const float2*>(&xs[cur][ci * 16 + sg * 2]);   // broadcast
      float4 w0 = *reinterpret_cast<const float4*>(&wt[cur][ci * 256 + dg * 4]);
      float4 w1 = *reinterpret_cast<const float4*>(&wt[cur][ci * 256 + 128 + dg * 4]);
      acc[0][0] = fmaf(xv.x, w0.x, acc[0][0]); acc[1][0] = fmaf(xv.y, w0.x, acc[1][0]);
      acc[0][1] = fmaf(xv.x, w0.y, acc[0][1]); acc[1][1] = fmaf(xv.y, w0.y, acc[1][1]);
      acc[0][2] = fmaf(xv.x, w0.z, acc[0][2]); acc[1][2] = fmaf(xv.y, w0.z, acc[1][2]);
      acc[0][3] = fmaf(xv.x, w0.w, acc[0][3]); acc[1][3] = fmaf(xv.y, w0.w, acc[1][3]);
      acc[0][4] = fmaf(xv.x, w1.x, acc[0][4]); acc[1][4] = fmaf(xv.y, w1.x, acc[1][4]);
      acc[0][5] = fmaf(xv.x, w1.y, acc[0][5]); acc[1][5] = fmaf(xv.y, w1.y, acc[1][5]);
      acc[0][6] = fmaf(xv.x, w1.z, acc[0][6]); acc[1][6] = fmaf(xv.y, w1.z, acc[1][6]);
      acc[0][7] = fmaf(xv.x, w1.w, acc[0][7]); acc[1][7] = fmaf(xv.y, w1.w, acc[1][7]);
    }
    cur ^= 1;   // safe: buf rewritten 2 iters later, after an intervening barrier
  }

  // bias add -> acc = att_x values; write att_x
  {
    float4 b0 = *reinterpret_cast<const float4*>(wv_b + dg * 4);
    float4 b1 = *reinterpret_cast<const float4*>(wv_b + 128 + dg * 4);
#pragma unroll
    for (int j = 0; j < 2; ++j) {
      acc[j][0] += b0.x; acc[j][1] += b0.y; acc[j][2] += b0.z; acc[j][3] += b0.w;
      acc[j][4] += b1.x; acc[j][5] += b1.y; acc[j][6] += b1.z; acc[j][7] += b1.w;
      float* dst = att_x + ((size_t)(b * SS + s0 + sg * 2 + j)) * DD + dg * 4;
      *reinterpret_cast<float4*>(dst)       = make_float4(acc[j][0], acc[j][1], acc[j][2], acc[j][3]);
      *reinterpret_cast<float4*>(dst + 128) = make_float4(acc[j][4], acc[j][5], acc[j][6], acc[j][7]);
    }
  }

  // ---- score phase: sc[t][s] = -2 * sum_d we_d * rcp(exp2(K2*att_x + att_rK) + 1) ----
  float4 we0 = *reinterpret_cast<const float4*>(we_w + dg * 4);
  float4 we1 = *reinterpret_cast<const float4*>(we_w + 128 + dg * 4);
  for (int t = 0; t < T; ++t) {
    const float4* arp = reinterpret_cast<const float4*>(att_rK + (size_t)t * DD + dg * 4);
    float4 a0 = arp[0];
    float4 a1 = arp[32];   // +128 floats
#pragma unroll
    for (int j = 0; j < 2; ++j) {
      float p = 0.f;
      p = fmaf(we0.x, fast_rcp(EXP2(fmaf(K2, acc[j][0], a0.x)) + 1.f), p);
      p = fmaf(we0.y, fast_rcp(EXP2(fmaf(K2, acc[j][1], a0.y)) + 1.f), p);
      p = fmaf(we0.z, fast_rcp(EXP2(fmaf(K2, acc[j][2], a0.z)) + 1.f), p);
      p = fmaf(we0.w, fast_rcp(EXP2(fmaf(K2, acc[j][3], a0.w)) + 1.f), p);
      p = fmaf(we1.x, fast_rcp(EXP2(fmaf(K2, acc[j][4], a1.x)) + 1.f), p);
      p = fmaf(we1.y, fast_rcp(EXP2(fmaf(K2, acc[j][5], a1.y)) + 1.f), p);
      p = fmaf(we1.z, fast_rcp(EXP2(fmaf(K2, acc[j][6], a1.z)) + 1.f), p);
      p = fmaf(we1.w, fast_rcp(EXP2(fmaf(K2, acc[j][7], a1.w)) + 1.f), p);
      // reduce over dg (lane bits 0..4) -> full d=256 sum
      p += __shfl_xor(p, 1);
      p += __shfl_xor(p, 2);
      p += __shfl_xor(p, 4);
      p += __shfl_xor(p, 8);
      p += __shfl_xor(p, 16);
      if (dg == 0) scS[t * 16 + sg * 2 + j] = -2.f * p;   // + const (softmax-invariant, dropped)
    }
  }
  __syncthreads();
  // coalesced score write: score[b][t][s0+sl]
  for (int idx = tid; idx < T * 16; idx += 256) {
    int t = idx >> 4, sl = idx & 15;
    score[((size_t)b * T + t) * SS + s0 + sl] = scS[idx];
  }
}

// ---- kernel 3 (FUSED): softmax over s + out[b][t][d] = (1/256)*sum_s alpha*att_x ----
// grid (64 b, 4 tg), block 1024: d = tid&255, scg = tid>>8.
__global__ __launch_bounds__(1024) void k_out2(
    const float* __restrict__ att_x, const float* __restrict__ score,
    float* __restrict__ out, int T)
{
  const int b  = blockIdx.x;
  const int tg = blockIdx.y;
  const int tchunk = (T + 3) >> 2;
  const int t0 = tg * tchunk;
  const int nT = (T - t0 < tchunk) ? (T - t0) : tchunk;
  if (nT <= 0) return;
  const int tid = threadIdx.x;
  const int d   = tid & 255;
  const int scg = tid >> 8;   // 0..3
  const int wv4 = (d >> 6);   // wave index within the 256-thread row group

  __shared__ float al[7 * 256];
  __shared__ float red[4 * 7 * 256];
  __shared__ float mred[8][4];
  __shared__ float sred[8][4];

  for (int idx = tid; idx < 7*256; idx += 1024)
    al[idx] = (idx < nT*256) ? score[((size_t)b*T + t0)*SS + idx] : 0.f;
  __syncthreads();

  // softmax over the 7 rows: row group scg handles rows {scg, scg+4}, uniform barriers
#pragma unroll
  for (int pass = 0; pass < 2; ++pass) {
    const int r = pass * 4 + scg;       // 0..7
    const bool live = (r < nT);
    float v = live ? al[r * 256 + d] : -3.0e38f;
    float m = v;
    m = fmaxf(m, __shfl_xor(m, 1));
    m = fmaxf(m, __shfl_xor(m, 2));
    m = fmaxf(m, __shfl_xor(m, 4));
    m = fmaxf(m, __shfl_xor(m, 8));
    m = fmaxf(m, __shfl_xor(m, 16));
    m = fmaxf(m, __shfl_xor(m, 32));
    if ((tid & 63) == 0) mred[r][wv4] = m;
    __syncthreads();
    float M = fmaxf(fmaxf(mred[r][0], mred[r][1]), fmaxf(mred[r][2], mred[r][3]));
    float ev = live ? EXP2((v - M) * LOG2E) : 0.f;
    float ss = ev;
    ss += __shfl_xor(ss, 1);
    ss += __shfl_xor(ss, 2);
    ss += __shfl_xor(ss, 4);
    ss += __shfl_xor(ss, 8);
    ss += __shfl_xor(ss, 16);
    ss += __shfl_xor(ss, 32);
    if ((tid & 63) == 0) sred[r][wv4] = ss;
    __syncthreads();
    float S = sred[r][0] + sred[r][1] + sred[r][2] + sred[r][3];
    if (live) al[r * 256 + d] = ev * fast_rcp(S);
  }
  __syncthreads();

  // weighted sum: thread sums its s-chunk (scg*64..+63) for all 7 t at fixed d
  float v[64];
  const float* ax = att_x + ((size_t)(b*SS) + scg*64) * DD + d;
#pragma unroll
  for (int i = 0; i < 64; ++i) v[i] = ax[(size_t)i * DD];

#pragma unroll
  for (int tl = 0; tl < 7; ++tl) {
    float a = 0.f;
#pragma unroll
    for (int i4 = 0; i4 < 16; ++i4) {
      float4 a4 = *reinterpret_cast<const float4*>(&al[tl*256 + scg*64 + i4*4]);  // wave-uniform
      a = fmaf(a4.x, v[i4*4+0], a);
      a = fmaf(a4.y, v[i4*4+1], a);
      a = fmaf(a4.z, v[i4*4+2], a);
      a = fmaf(a4.w, v[i4*4+3], a);
    }
    red[scg*1792 + tl*256 + d] = a;
  }
  __syncthreads();
  for (int idx = tid; idx < nT*256; idx += 1024) {
    float sum = red[idx] + red[1792 + idx] + red[2*1792 + idx] + red[3*1792 + idx];
    out[((size_t)b*T + t0)*SS + idx] = sum * (1.0f/256.0f);
  }
}

extern "C" void kernel_launch(void* const* d_in, const int* in_sizes, int n_in,
                              void* d_out, int out_size, void* d_ws, size_t ws_size,
                              hipStream_t stream) {
  (void)in_sizes; (void)n_in; (void)ws_size;
  const float* x    = (const float*)d_in[0];
  // d_in[1] = seq_len (device int scalar) -- T derived from out_size instead
  const float* wo_w = (const float*)d_in[2];
  const float* wo_b = (const float*)d_in[3];
  const float* wv_w = (const float*)d_in[4];
  const float* wv_b = (const float*)d_in[5];
  const float* we_w = (const float*)d_in[6];
  float* out = (float*)d_out;
  const int T = out_size / (BB * DD);

  float* att_x = (float*)d_ws;                     // 64*256*256 floats (16 MB)
  float* wvT   = att_x + (size_t)BB * SS * DD;     // 65536 floats
  float* att_r = wvT + DD * DD;                    // 64*DD reserved (K2-scaled)
  float* score = att_r + 64 * DD;                  // B*T*256 floats (raw scores)

  k_prep       <<<dim3(16 + T), 256, 0, stream>>>(wv_w, wo_w, wo_b, wvT, att_r, T);
  k_attx_score <<<dim3(16, BB), 256, 0, stream>>>(x, wvT, wv_b, att_r, we_w, att_x, score, T);
  k_out2       <<<dim3(BB, 4), 1024, 0, stream>>>(att_x, score, out, T);
}

// Round 9
// 83.184 us; speedup vs baseline: 1.5948x; 1.5948x over previous
//
#include <hip/hip_runtime.h>

#define DD 256
#define BB 64
#define SS 256                       // H*W
#define K2 2.8853900817779268f      // 2*log2(e)
#define LOG2E 1.4426950408889634f
#define MAXT 32

#if __has_builtin(__builtin_amdgcn_exp2f)
#define EXP2(x) __builtin_amdgcn_exp2f(x)
#else
#define EXP2(x) exp2f(x)
#endif

static __device__ __forceinline__ float fast_rcp(float x) {
  return __builtin_amdgcn_rcpf(x);
}

// ---- kernel 1: transpose wv_w into wvT (blocks 0..15) + att_r = pe@wo^T+b (blocks 16..16+T) ----
__global__ __launch_bounds__(256) void k_prep(
    const float* __restrict__ wv_w,
    const float* __restrict__ wo_w, const float* __restrict__ wo_b,
    float* __restrict__ wvT, float* __restrict__ att_r, int T)
{
  const int tid = threadIdx.x;
  if (blockIdx.x < 16) {
    const int bi = blockIdx.x >> 2;   // d-tile
    const int bj = blockIdx.x & 3;    // c-tile
    __shared__ float tile[64 * 65];
#pragma unroll
    for (int p = 0; p < 4; ++p) {
      int row = p * 16 + (tid >> 4);          // local d
      int col = (tid & 15) * 4;               // local c
      float4 v = *reinterpret_cast<const float4*>(wv_w + (size_t)(bi*64 + row)*DD + bj*64 + col);
      tile[row*65 + col + 0] = v.x;
      tile[row*65 + col + 1] = v.y;
      tile[row*65 + col + 2] = v.z;
      tile[row*65 + col + 3] = v.w;
    }
    __syncthreads();
#pragma unroll
    for (int p = 0; p < 4; ++p) {
      int orow = p * 16 + (tid >> 4);   // local c
      int ocol = (tid & 15) * 4;        // local d
      float4 o;
      o.x = tile[(ocol+0)*65 + orow];
      o.y = tile[(ocol+1)*65 + orow];
      o.z = tile[(ocol+2)*65 + orow];
      o.w = tile[(ocol+3)*65 + orow];
      *reinterpret_cast<float4*>(wvT + (size_t)(bj*64 + orow)*DD + bi*64 + ocol) = o;
    }
    return;
  }
  // ---- att_r branch ----
  const int t = blockIdx.x - 16;
  if (t >= T) return;
  __shared__ float pe[DD];
  {
    int i = tid >> 1;
    double r = pow(10000.0, -(double)(2*i) / 256.0);
    double ang = (double)t * r;
    pe[tid] = (float)((tid & 1) ? cos(ang) : sin(ang));
  }
  __syncthreads();
  const float4* wr = reinterpret_cast<const float4*>(wo_w + (size_t)tid * DD);
  const float4* pp = reinterpret_cast<const float4*>(pe);
  float acc = 0.f;
#pragma unroll 8
  for (int k = 0; k < 64; ++k) {
    float4 w4 = wr[k]; float4 p4 = pp[k];
    acc = fmaf(w4.x, p4.x, acc);
    acc = fmaf(w4.y, p4.y, acc);
    acc = fmaf(w4.z, p4.z, acc);
    acc = fmaf(w4.w, p4.w, acc);
  }
  att_r[(size_t)t*DD + tid] = acc + wo_b[tid];
}

// ---- kernel 2: att_x[b][s][d] = sum_c x[b][c][s] * wvT[c][d] + wv_b[d] ----
// grid (4 sT, 2 dT, 64 b) = 512 blocks, block 256. Tile 64s x 128d.
// Thread 8s x 4d (acc[8][4]): 256 x 32 = 8192 = 64*128 exact cover.
// w-LDS cost 0.5 B/FMA (32 FMA per 16B w-read). Dbuf LDS, ONE barrier/chunk.
__global__ __launch_bounds__(256) void k_attx(
    const float* __restrict__ x, const float* __restrict__ wvT,
    const float* __restrict__ wv_b, float* __restrict__ att_x)
{
  const int b  = blockIdx.z;
  const int dT = blockIdx.y;           // 0..1 -> d-half
  const int s0 = blockIdx.x * 64;
  const int tid = threadIdx.x;
  const int sg = tid >> 5;             // 0..7 -> s = s0 + sg*8 + j
  const int dg = tid & 31;             // 0..31 -> d = dT*128 + dg*4
  const float* xb = x + (size_t)b * DD * SS;   // [c][s]

  __shared__ float wt[2][16 * 128];    // 2 x 8 KB   [c][d-local]
  __shared__ float xs[2][16 * 64];     // 2 x 4 KB   [c][s-local]

  float acc[8][4];
#pragma unroll
  for (int j = 0; j < 8; ++j)
#pragma unroll
    for (int r = 0; r < 4; ++r) acc[j][r] = 0.f;

  // staging (flat, coalesced, lane-consecutive LDS writes)
  // wt flat[tid*4 + k*1024] <- wvT[cc*16 + (tid>>5) + 8k][dT*128 + (tid&31)*4]
  const float* wsrc0 = wvT + (size_t)(tid >> 5) * DD + dT * 128 + (tid & 31) * 4;
  const float* wsrc1 = wsrc0 + (size_t)8 * DD;
  // xs flat[tid*4] <- x[b][cc*16 + (tid>>4)][s0 + (tid&15)*4]
  const float* xsrc = xb + (size_t)(tid >> 4) * SS + s0 + (tid & 15) * 4;

  float4 wA0 = *reinterpret_cast<const float4*>(wsrc0);
  float4 wA1 = *reinterpret_cast<const float4*>(wsrc1);
  float4 xA  = *reinterpret_cast<const float4*>(xsrc);

  int cur = 0;
  for (int cc = 0; cc < 16; ++cc) {
    *reinterpret_cast<float4*>(&wt[cur][tid * 4])        = wA0;
    *reinterpret_cast<float4*>(&wt[cur][1024 + tid * 4]) = wA1;
    *reinterpret_cast<float4*>(&xs[cur][tid * 4])        = xA;
    if (cc < 15) {                                  // prefetch next chunk -> regs
      wA0 = *reinterpret_cast<const float4*>(wsrc0 + (size_t)(cc + 1) * 16 * DD);
      wA1 = *reinterpret_cast<const float4*>(wsrc1 + (size_t)(cc + 1) * 16 * DD);
      xA  = *reinterpret_cast<const float4*>(xsrc  + (size_t)(cc + 1) * 16 * SS);
    }
    __syncthreads();                                // buf[cur] ready
#pragma unroll
    for (int ci = 0; ci < 16; ++ci) {
      // x: 2 b128 broadcast (2 distinct addrs/wave)
      float4 x0 = *reinterpret_cast<const float4*>(&xs[cur][ci * 64 + sg * 8]);
      float4 x1 = *reinterpret_cast<const float4*>(&xs[cur][ci * 64 + sg * 8 + 4]);
      // w: 1 b128 lane-consecutive (full-BW pattern)
      float4 w0 = *reinterpret_cast<const float4*>(&wt[cur][ci * 128 + dg * 4]);
      const float xv[8] = {x0.x, x0.y, x0.z, x0.w, x1.x, x1.y, x1.z, x1.w};
#pragma unroll
      for (int j = 0; j < 8; ++j) {
        acc[j][0] = fmaf(xv[j], w0.x, acc[j][0]);
        acc[j][1] = fmaf(xv[j], w0.y, acc[j][1]);
        acc[j][2] = fmaf(xv[j], w0.z, acc[j][2]);
        acc[j][3] = fmaf(xv[j], w0.w, acc[j][3]);
      }
    }
    cur ^= 1;   // safe: buf rewritten 2 iterations later, after an intervening barrier
  }

  float4 bv = *reinterpret_cast<const float4*>(wv_b + dT * 128 + dg * 4);
#pragma unroll
  for (int j = 0; j < 8; ++j) {
    float4 o;
    o.x = acc[j][0] + bv.x; o.y = acc[j][1] + bv.y;
    o.z = acc[j][2] + bv.z; o.w = acc[j][3] + bv.w;
    float* dst = att_x + ((size_t)(b * SS + s0 + sg * 8 + j)) * DD + dT * 128 + dg * 4;
    *reinterpret_cast<float4*>(dst) = o;
  }
}

// ---- kernel 3: raw scores (no softmax).  grid (4 s-tiles of 64, 64 b), block 1024. ----
// thread: s = tid>>4 (64 s/block), c = tid&15 owns d in [c*16, c*16+16).
__global__ __launch_bounds__(1024) void k_score2(
    const float* __restrict__ att_x, const float* __restrict__ att_r,
    const float* __restrict__ we_w, float* __restrict__ score, int T)
{
  const int b  = blockIdx.y;
  const int s0 = blockIdx.x * 64;
  const int tid = threadIdx.x;
  const int s  = tid >> 4;       // 0..63
  const int c  = tid & 15;       // 0..15

  __shared__ float attrS[MAXT * 320];   // [t][c*20 + j], c-stride 20: 2-way bank alias (free)
  __shared__ float scS[MAXT * 64];

  float f0x, f0y, f0z, f0w, f1x, f1y, f1z, f1w;
  float f2x, f2y, f2z, f2w, f3x, f3y, f3z, f3w;
  {
    const float4* ax4 = reinterpret_cast<const float4*>(
        att_x + ((size_t)(b * SS + s0 + s)) * DD + c * 16);
    float4 a = ax4[0], bq = ax4[1], cq = ax4[2], dq = ax4[3];
    f0x = a.x*K2;  f0y = a.y*K2;  f0z = a.z*K2;  f0w = a.w*K2;
    f1x = bq.x*K2; f1y = bq.y*K2; f1z = bq.z*K2; f1w = bq.w*K2;
    f2x = cq.x*K2; f2y = cq.y*K2; f2z = cq.z*K2; f2w = cq.w*K2;
    f3x = dq.x*K2; f3y = dq.y*K2; f3z = dq.z*K2; f3w = dq.w*K2;
  }
  float4 w0, w1, w2, w3;
  {
    const float4* we4 = reinterpret_cast<const float4*>(we_w + c * 16);
    w0 = we4[0]; w1 = we4[1]; w2 = we4[2]; w3 = we4[3];
  }
  for (int idx = tid; idx < T * 256; idx += 1024) {
    int t = idx >> 8, d = idx & 255;
    attrS[t * 320 + (d >> 4) * 20 + (d & 15)] = att_r[(size_t)t * DD + d] * K2;
  }
  __syncthreads();

  for (int tl = 0; tl < T; ++tl) {
    const float* aS = &attrS[tl * 320 + c * 20];
    float4 a0 = *reinterpret_cast<const float4*>(aS);
    float4 a1 = *reinterpret_cast<const float4*>(aS + 4);
    float4 a2 = *reinterpret_cast<const float4*>(aS + 8);
    float4 a3 = *reinterpret_cast<const float4*>(aS + 12);
    float part = 0.f;
    part = fmaf(w0.x, fast_rcp(EXP2(f0x + a0.x) + 1.f), part);
    part = fmaf(w0.y, fast_rcp(EXP2(f0y + a0.y) + 1.f), part);
    part = fmaf(w0.z, fast_rcp(EXP2(f0z + a0.z) + 1.f), part);
    part = fmaf(w0.w, fast_rcp(EXP2(f0w + a0.w) + 1.f), part);
    part = fmaf(w1.x, fast_rcp(EXP2(f1x + a1.x) + 1.f), part);
    part = fmaf(w1.y, fast_rcp(EXP2(f1y + a1.y) + 1.f), part);
    part = fmaf(w1.z, fast_rcp(EXP2(f1z + a1.z) + 1.f), part);
    part = fmaf(w1.w, fast_rcp(EXP2(f1w + a1.w) + 1.f), part);
    part = fmaf(w2.x, fast_rcp(EXP2(f2x + a2.x) + 1.f), part);
    part = fmaf(w2.y, fast_rcp(EXP2(f2y + a2.y) + 1.f), part);
    part = fmaf(w2.z, fast_rcp(EXP2(f2z + a2.z) + 1.f), part);
    part = fmaf(w2.w, fast_rcp(EXP2(f2w + a2.w) + 1.f), part);
    part = fmaf(w3.x, fast_rcp(EXP2(f3x + a3.x) + 1.f), part);
    part = fmaf(w3.y, fast_rcp(EXP2(f3y + a3.y) + 1.f), part);
    part = fmaf(w3.z, fast_rcp(EXP2(f3z + a3.z) + 1.f), part);
    part = fmaf(w3.w, fast_rcp(EXP2(f3w + a3.w) + 1.f), part);
    part += __shfl_xor(part, 1);
    part += __shfl_xor(part, 2);
    part += __shfl_xor(part, 4);
    part += __shfl_xor(part, 8);
    if (c == 0) scS[tl * 64 + s] = -2.f * part;   // + softmax-invariant const (dropped)
  }
  __syncthreads();
  for (int idx = tid; idx < T * 64; idx += 1024) {
    int t = idx >> 6, sl = idx & 63;
    score[((size_t)b * T + t) * SS + s0 + sl] = scS[idx];
  }
}

// ---- kernel 4 (FUSED): softmax over s + out[b][t][d] = (1/256)*sum_s alpha*att_x ----
// grid (64 b, 4 tg), block 1024: d = tid&255, scg = tid>>8.
__global__ __launch_bounds__(1024) void k_out2(
    const float* __restrict__ att_x, const float* __restrict__ score,
    float* __restrict__ out, int T)
{
  const int b  = blockIdx.x;
  const int tg = blockIdx.y;
  const int tchunk = (T + 3) >> 2;
  const int t0 = tg * tchunk;
  const int nT = (T - t0 < tchunk) ? (T - t0) : tchunk;
  if (nT <= 0) return;
  const int tid = threadIdx.x;
  const int d   = tid & 255;
  const int scg = tid >> 8;   // 0..3
  const int wv4 = (d >> 6);

  __shared__ float al[7 * 256];
  __shared__ float red[4 * 7 * 256];
  __shared__ float mred[8][4];
  __shared__ float sred[8][4];

  for (int idx = tid; idx < 7*256; idx += 1024)
    al[idx] = (idx < nT*256) ? score[((size_t)b*T + t0)*SS + idx] : 0.f;
  __syncthreads();

#pragma unroll
  for (int pass = 0; pass < 2; ++pass) {
    const int r = pass * 4 + scg;       // 0..7
    const bool live = (r < nT);
    float v = live ? al[r * 256 + d] : -3.0e38f;
    float m = v;
    m = fmaxf(m, __shfl_xor(m, 1));
    m = fmaxf(m, __shfl_xor(m, 2));
    m = fmaxf(m, __shfl_xor(m, 4));
    m = fmaxf(m, __shfl_xor(m, 8));
    m = fmaxf(m, __shfl_xor(m, 16));
    m = fmaxf(m, __shfl_xor(m, 32));
    if ((tid & 63) == 0) mred[r][wv4] = m;
    __syncthreads();
    float M = fmaxf(fmaxf(mred[r][0], mred[r][1]), fmaxf(mred[r][2], mred[r][3]));
    float ev = live ? EXP2((v - M) * LOG2E) : 0.f;
    float ss = ev;
    ss += __shfl_xor(ss, 1);
    ss += __shfl_xor(ss, 2);
    ss += __shfl_xor(ss, 4);
    ss += __shfl_xor(ss, 8);
    ss += __shfl_xor(ss, 16);
    ss += __shfl_xor(ss, 32);
    if ((tid & 63) == 0) sred[r][wv4] = ss;
    __syncthreads();
    float S = sred[r][0] + sred[r][1] + sred[r][2] + sred[r][3];
    if (live) al[r * 256 + d] = ev * fast_rcp(S);
  }
  __syncthreads();

  float v[64];
  const float* ax = att_x + ((size_t)(b*SS) + scg*64) * DD + d;
#pragma unroll
  for (int i = 0; i < 64; ++i) v[i] = ax[(size_t)i * DD];

#pragma unroll
  for (int tl = 0; tl < 7; ++tl) {
    float a = 0.f;
#pragma unroll
    for (int i4 = 0; i4 < 16; ++i4) {
      float4 a4 = *reinterpret_cast<const float4*>(&al[tl*256 + scg*64 + i4*4]);  // wave-uniform
      a = fmaf(a4.x, v[i4*4+0], a);
      a = fmaf(a4.y, v[i4*4+1], a);
      a = fmaf(a4.z, v[i4*4+2], a);
      a = fmaf(a4.w, v[i4*4+3], a);
    }
    red[scg*1792 + tl*256 + d] = a;
  }
  __syncthreads();
  for (int idx = tid; idx < nT*256; idx += 1024) {
    float sum = red[idx] + red[1792 + idx] + red[2*1792 + idx] + red[3*1792 + idx];
    out[((size_t)b*T + t0)*SS + idx] = sum * (1.0f/256.0f);
  }
}

extern "C" void kernel_launch(void* const* d_in, const int* in_sizes, int n_in,
                              void* d_out, int out_size, void* d_ws, size_t ws_size,
                              hipStream_t stream) {
  (void)in_sizes; (void)n_in; (void)ws_size;
  const float* x    = (const float*)d_in[0];
  // d_in[1] = seq_len (device int scalar) -- T derived from out_size instead
  const float* wo_w = (const float*)d_in[2];
  const float* wo_b = (const float*)d_in[3];
  const float* wv_w = (const float*)d_in[4];
  const float* wv_b = (const float*)d_in[5];
  const float* we_w = (const float*)d_in[6];
  float* out = (float*)d_out;
  const int T = out_size / (BB * DD);

  float* att_x = (float*)d_ws;                     // 64*256*256 floats (16 MB)
  float* wvT   = att_x + (size_t)BB * SS * DD;     // 65536 floats
  float* att_r = wvT + DD * DD;                    // 64*DD reserved
  float* score = att_r + 64 * DD;                  // B*T*256 floats (raw scores)

  k_prep   <<<dim3(16 + T), 256, 0, stream>>>(wv_w, wo_w, wo_b, wvT, att_r, T);
  k_attx   <<<dim3(4, 2, BB), 256, 0, stream>>>(x, wvT, wv_b, att_x);
  k_score2 <<<dim3(4, BB), 1024, 0, stream>>>(att_x, att_r, we_w, score, T);
  k_out2   <<<dim3(BB, 4), 1024, 0, stream>>>(att_x, score, out, T);
}